// Round 3
// baseline (924.930 us; speedup 1.0000x reference)
//
#include <hip/hip_runtime.h>
#include <hip/hip_bf16.h>
#include <math.h>

#define BB 8
#define SS 512
#define LIN_SCALE 0.044194173824159216f   // 1/sqrt(512)
#define CONV_SCALE 0.041666666666666664f  // 1/sqrt(64*9)
#define SQRT2 1.4142135623730951f

typedef __attribute__((ext_vector_type(8))) short short8;
typedef __attribute__((ext_vector_type(16))) float f32x16;

__device__ __forceinline__ ushort bf16h(float v) {
    unsigned u = __float_as_uint(v);
    return (ushort)((u + 0x7fffu + ((u >> 16) & 1u)) >> 16);
}
__device__ __forceinline__ void splitv(float v, ushort& h, ushort& l) {
    h = bf16h(v);
    l = bf16h(v - __uint_as_float((unsigned)h << 16));
}
__device__ __forceinline__ float b2f(ushort u) { return __uint_as_float((unsigned)u << 16); }

// ---------------------------------------------------------------------------
// prep kernels
// ---------------------------------------------------------------------------
__global__ void zero_k(float* z) { z[threadIdx.x] = 0.f; }   // 64 thr -> 256 B

// NCHW fp32 -> channels-last bf16 hi/lo planes
__global__ __launch_bounds__(256) void tocl_k(const float* __restrict__ x,
                                              ushort* __restrict__ oH, ushort* __restrict__ oL) {
    __shared__ float tile[64][65];
    const int blk = blockIdx.x;                  // 8*256*4
    const int b = blk >> 10, rem = blk & 1023;
    const int y = rem >> 2, x0 = (rem & 3) << 6;
    const int tid = threadIdx.x, lane = tid & 63, g = tid >> 6;
    const float* xb = x + ((size_t)b << 22) + (y << 8) + x0;
    #pragma unroll
    for (int i = 0; i < 16; ++i) {
        int c = i * 4 + g;
        tile[c][lane] = xb[((size_t)c << 16) + lane];
    }
    __syncthreads();
    const size_t pixbase = ((size_t)b << 16) + (y << 8) + x0;
    #pragma unroll
    for (int i = 0; i < 16; ++i) {
        int xx = i * 4 + g;
        ushort h, l; splitv(tile[lane][xx], h, l);
        size_t idx = (pixbase + xx) * 64 + lane;
        oH[idx] = h; oL[idx] = l;
    }
}

// pack OIHW fp32 weights -> pre-swizzled LDS image: 4 chunks x [secH|secL] x [t][co][spos][8e]
__device__ __forceinline__ void wdecode(int ii, int& cc, int& sec, int& t, int& co, int& spos, int& e) {
    cc = ii / 18432; int r1 = ii % 18432;
    sec = r1 / 9216;  int r2 = r1 % 9216;
    t = r2 / 1024;    int r3 = r2 % 1024;
    co = r3 >> 4;     int r4 = r3 & 15;
    spos = r4 >> 3;   e = r4 & 7;
}

__global__ void packw_k(const float* __restrict__ w, ushort* __restrict__ img) {
    int i = blockIdx.x * 256 + threadIdx.x;      // 73728
    if (i >= 73728) return;
    int cc, sec, t, co, spos, e;
    wdecode(i, cc, sec, t, co, spos, e);
    int ci = cc * 16 + ((spos ^ ((co >> 2) & 1)) << 3) + e;
    ushort h, l; splitv(w[(co * 64 + ci) * 9 + t], h, l);
    img[i] = sec ? l : h;
}

__global__ void style_s_k(const float* __restrict__ style, const float* __restrict__ mod_w,
                          const float* __restrict__ mod_b, float* __restrict__ sbuf) {
    int tid = threadIdx.x;                       // 512
    int b = tid >> 6, cin = tid & 63;
    float acc = 0.f;
    for (int j = 0; j < SS; ++j) acc += style[b * SS + j] * mod_w[cin * SS + j];
    sbuf[b * 64 + cin] = acc * LIN_SCALE + mod_b[cin];
}

__global__ void demod_k(const float* __restrict__ conv_w, const float* __restrict__ sbuf,
                        float* __restrict__ demod) {
    int tid = threadIdx.x;                       // 512
    int b = tid >> 6, cout = tid & 63;
    float sum = 0.f;
    for (int cin = 0; cin < 64; ++cin) {
        float m = CONV_SCALE * sbuf[b * 64 + cin];
        const float* wp = conv_w + (cout * 64 + cin) * 9;
        #pragma unroll
        for (int k = 0; k < 9; ++k) { float v = wp[k] * m; sum += v * v; }
    }
    demod[b * 64 + cout] = 1.0f / sqrtf(sum + 1e-8f);
}

__global__ void packmod_k(const float* __restrict__ conv_w, const float* __restrict__ sbuf,
                          const float* __restrict__ demod, ushort* __restrict__ img) {
    int i = blockIdx.x * 256 + threadIdx.x;      // 589824
    if (i >= 589824) return;
    int b = i / 73728, ii = i % 73728;
    int cc, sec, t, co, spos, e;
    wdecode(ii, cc, sec, t, co, spos, e);
    int ci = cc * 16 + ((spos ^ ((co >> 2) & 1)) << 3) + e;
    float v = CONV_SCALE * conv_w[(co * 64 + ci) * 9 + t] * sbuf[b * 64 + ci] * demod[b * 64 + co];
    ushort h, l; splitv(v, h, l);
    img[i] = sec ? l : h;
}

// ---------------------------------------------------------------------------
// MFMA conv: 3x3 C64->C64 SAME. Inputs: pre-split bf16 H/L channels-last.
// Block 256 thr = 4 waves, tile 8 rows x 32 px, 64 couts; per wave 2x2
// 32x32x16 frags. K chunked 16 cins; async global_load_lds pipeline:
// input double-buffered, weights single-buffered, counted vmcnt(5).
// LDS per buffer: [intH 640sl][intL 640sl][haloH 40sl][haloL 40sl] = 21760 B.
// Weights at 43520: [WH 1152sl][WL 1152sl] = 36864 B. Total 80384 B.
// EPI: 0 = PReLU->pair, 1 = +resid(pair)->pair, 2 = fusedLReLU->NCHW fp32.
// ---------------------------------------------------------------------------
#define GLDS(gsrc, ldst) __builtin_amdgcn_global_load_lds( \
    (const __attribute__((address_space(1))) unsigned int*)(gsrc), \
    (__attribute__((address_space(3))) unsigned int*)(ldst), 16, 0, 0)

#define VWAIT(n) asm volatile("s_waitcnt vmcnt(" #n ")" ::: "memory")
#define LWAIT    asm volatile("s_waitcnt lgkmcnt(0)" ::: "memory")
#define BAR      __builtin_amdgcn_s_barrier()
#define SCB      __builtin_amdgcn_sched_barrier(0)

template <int EPI, int PERB>
__global__ __launch_bounds__(256, 2)
void mconv_k(const ushort* __restrict__ inH, const ushort* __restrict__ inL,
             const char* __restrict__ wimg, const float* __restrict__ aux,
             const ushort* __restrict__ rH, const ushort* __restrict__ rL,
             ushort* __restrict__ oH, ushort* __restrict__ oL,
             float* __restrict__ onchw, const ushort* __restrict__ zb) {
    __shared__ __align__(16) char lds[80384];
    const int tid = threadIdx.x;
    const int orig = blockIdx.x;
    const int blk = (orig & 7) * 256 + (orig >> 3);   // XCD swizzle (2048 % 8 == 0)
    const int b = blk >> 8, t8 = blk & 255;
    const int y0 = (t8 >> 3) << 3, x0 = (t8 & 7) << 5;
    const int wv = tid >> 6, l = tid & 63, ln = l & 31, lh = l >> 5;

    // per-lane async source addresses for the 5 interior staging rounds
    const ushort* iaddr[5];
    #pragma unroll
    for (int r = 0; r < 5; ++r) {
        int g = r * 256 + tid;
        int isL = g >= 640;
        int gg = g - (isL ? 640 : 0);
        int p = gg >> 1, sl = gg & 1;
        int h = sl ^ ((p >> 2) & 1);          // pre-swizzled source half
        int row = p >> 5, xi = p & 31;
        int gy = y0 - 1 + row;
        const ushort* base = isL ? inL : inH;
        iaddr[r] = ((unsigned)gy < 256u)
            ? base + ((((size_t)b << 16) + ((size_t)gy << 8) + (x0 + xi)) << 6) + (h << 3)
            : zb;
    }
    const char* wsrc = wimg + (PERB ? (size_t)b * 147456 : 0);
    const int aswz = lh ^ ((ln >> 2) & 1);
    const int aoff0 = 43520 + ln * 32 + aswz * 16;    // +t*2048, +m*1024, +18432 for L

    f32x16 acc[2][2];
    #pragma unroll
    for (int m = 0; m < 2; ++m)
        #pragma unroll
        for (int j = 0; j < 2; ++j) acc[m][j] = (f32x16)(0.0f);

#define ISSUE_I(c, bo) { _Pragma("unroll") for (int r = 0; r < 5; ++r) \
    GLDS(iaddr[r] + (c) * 16, lds + (bo) + r * 4096 + (tid & 192) * 16); }
#define ISSUE_W(c) { _Pragma("unroll") for (int r = 0; r < 9; ++r) \
    GLDS(wsrc + (c) * 36864 + r * 4096 + tid * 16, lds + 43520 + r * 4096 + (tid & 192) * 16); }
#define HALO_LD(cx, V, D) { D = 0; if (tid < 80) { \
    int hp = tid >> 2, s = tid & 3; \
    int row = hp >> 1, side = hp & 1; \
    int gy = y0 - 1 + row, gx = side ? x0 + 32 : x0 - 1; \
    int pl = s >> 1, hh = s & 1; \
    const ushort* bse = pl ? inL : inH; \
    const ushort* a = (((unsigned)gy < 256u) & ((unsigned)gx < 256u)) \
        ? bse + ((((size_t)b << 16) + ((size_t)gy << 8) + gx) << 6) + (cx) * 16 + (hh << 3) : zb; \
    V = *(const uint4*)a; \
    D = (pl ? 21120 : 20480) + (hp * 2 + hh) * 16; } }
#define HALO_WR(bo, V, D) { if (tid < 80) *(uint4*)(lds + (bo) + D) = V; }
#define COMPUTE(bo) { const char* IB = lds + (bo); \
  _Pragma("unroll") for (int dx = 0; dx < 3; ++dx) { \
    short8 cbH[4], cbL[4]; \
    _Pragma("unroll") for (int rw = 0; rw < 4; ++rw) { \
      int rr = 2 * wv + rw, xx = ln + dx; \
      int p = rr * 32 + xx - 1; \
      int offI = p * 32 + (lh ^ ((p >> 2) & 1)) * 16; \
      int hal = (xx == 0) | (xx == 33); \
      int offH = 20480 + (rr * 2 + (xx != 0)) * 32 + lh * 16; \
      int off = hal ? offH : offI; \
      int dL = hal ? 640 : 10240; \
      cbH[rw] = *(const short8*)(IB + off); \
      cbL[rw] = *(const short8*)(IB + off + dL); } \
    _Pragma("unroll") for (int dy = 0; dy < 3; ++dy) { \
      const char* WA = lds + (dy * 3 + dx) * 2048; \
      short8 aH0 = *(const short8*)(WA + aoff0); \
      short8 aH1 = *(const short8*)(WA + aoff0 + 1024); \
      short8 aL0 = *(const short8*)(WA + aoff0 + 18432); \
      short8 aL1 = *(const short8*)(WA + aoff0 + 18432 + 1024); \
      _Pragma("unroll") for (int j = 0; j < 2; ++j) { \
        acc[0][j] = __builtin_amdgcn_mfma_f32_32x32x16_bf16(aH0, cbH[j + dy], acc[0][j], 0, 0, 0); \
        acc[0][j] = __builtin_amdgcn_mfma_f32_32x32x16_bf16(aH0, cbL[j + dy], acc[0][j], 0, 0, 0); \
        acc[0][j] = __builtin_amdgcn_mfma_f32_32x32x16_bf16(aL0, cbH[j + dy], acc[0][j], 0, 0, 0); \
        acc[1][j] = __builtin_amdgcn_mfma_f32_32x32x16_bf16(aH1, cbH[j + dy], acc[1][j], 0, 0, 0); \
        acc[1][j] = __builtin_amdgcn_mfma_f32_32x32x16_bf16(aH1, cbL[j + dy], acc[1][j], 0, 0, 0); \
        acc[1][j] = __builtin_amdgcn_mfma_f32_32x32x16_bf16(aL1, cbH[j + dy], acc[1][j], 0, 0, 0); } } } }

    uint4 hv, hv2; int hd, hd2;
    // ---- prologue: stage chunks 0,1 ----
    HALO_LD(0, hv, hd); HALO_LD(1, hv2, hd2);
    SCB;
    ISSUE_W(0); ISSUE_I(0, 0); ISSUE_I(1, 21760);
    SCB;
    HALO_WR(0, hv, hd); HALO_WR(21760, hv2, hd2);
    SCB;
    // ---- iter 0 ----
    VWAIT(5); LWAIT; BAR; SCB;
    COMPUTE(0);
    SCB; BAR;
    HALO_LD(2, hv, hd); SCB;
    ISSUE_W(1); ISSUE_I(2, 0); SCB;
    HALO_WR(0, hv, hd); SCB;
    // ---- iter 1 ----
    VWAIT(5); LWAIT; BAR; SCB;
    COMPUTE(21760);
    SCB; BAR;
    HALO_LD(3, hv, hd); SCB;
    ISSUE_W(2); ISSUE_I(3, 21760); SCB;
    HALO_WR(21760, hv, hd); SCB;
    // ---- iter 2 ----
    VWAIT(5); LWAIT; BAR; SCB;
    COMPUTE(0);
    SCB; BAR;
    ISSUE_W(3); SCB;
    // ---- iter 3 ----
    VWAIT(0); LWAIT; BAR; SCB;
    COMPUTE(21760);
    SCB;

#undef ISSUE_I
#undef ISSUE_W
#undef HALO_LD
#undef HALO_WR
#undef COMPUTE

    // ---- epilogue: C/D col = ln(px), row = 8q + 4lh + (0..3), +32m ----
    #pragma unroll
    for (int m = 0; m < 2; ++m)
        #pragma unroll
        for (int j = 0; j < 2; ++j) {
            const int yo = y0 + 2 * wv + j;
            const size_t pix = ((size_t)b << 16) + ((size_t)yo << 8) + x0 + ln;
            #pragma unroll
            for (int q = 0; q < 4; ++q) {
                const int co0 = m * 32 + 8 * q + 4 * lh;
                float v0 = acc[m][j][4 * q + 0], v1 = acc[m][j][4 * q + 1];
                float v2 = acc[m][j][4 * q + 2], v3 = acc[m][j][4 * q + 3];
                if (EPI == 0) {
                    float4 al = *(const float4*)(aux + co0);
                    v0 = v0 > 0.f ? v0 : al.x * v0;
                    v1 = v1 > 0.f ? v1 : al.y * v1;
                    v2 = v2 > 0.f ? v2 : al.z * v2;
                    v3 = v3 > 0.f ? v3 : al.w * v3;
                } else if (EPI == 1) {
                    const size_t ca = pix * 64 + co0;
                    ushort4 rh = *(const ushort4*)(rH + ca);
                    ushort4 rl = *(const ushort4*)(rL + ca);
                    v0 += b2f(rh.x) + b2f(rl.x);
                    v1 += b2f(rh.y) + b2f(rl.y);
                    v2 += b2f(rh.z) + b2f(rl.z);
                    v3 += b2f(rh.w) + b2f(rl.w);
                } else {
                    float4 bi = *(const float4*)(aux + co0);
                    float ob;
                    ob = v0 + bi.x; v0 = (ob > 0.f ? ob : 0.2f * ob) * SQRT2;
                    ob = v1 + bi.y; v1 = (ob > 0.f ? ob : 0.2f * ob) * SQRT2;
                    ob = v2 + bi.z; v2 = (ob > 0.f ? ob : 0.2f * ob) * SQRT2;
                    ob = v3 + bi.w; v3 = (ob > 0.f ? ob : 0.2f * ob) * SQRT2;
                }
                if (EPI == 2) {
                    const size_t sp = ((size_t)yo << 8) + x0 + ln;
                    onchw[(((size_t)(b * 64 + co0 + 0)) << 16) + sp] = v0;
                    onchw[(((size_t)(b * 64 + co0 + 1)) << 16) + sp] = v1;
                    onchw[(((size_t)(b * 64 + co0 + 2)) << 16) + sp] = v2;
                    onchw[(((size_t)(b * 64 + co0 + 3)) << 16) + sp] = v3;
                } else {
                    ushort4 h4, l4;
                    splitv(v0, h4.x, l4.x); splitv(v1, h4.y, l4.y);
                    splitv(v2, h4.z, l4.z); splitv(v3, h4.w, l4.w);
                    const size_t ca = pix * 64 + co0;
                    *(ushort4*)(oH + ca) = h4;
                    *(ushort4*)(oL + ca) = l4;
                }
            }
        }
}

// ---------------------------------------------------------------------------
// Host launch
// ---------------------------------------------------------------------------
extern "C" void kernel_launch(void* const* d_in, const int* in_sizes, int n_in,
                              void* d_out, int out_size, void* d_ws, size_t ws_size,
                              hipStream_t stream) {
    const float* x       = (const float*)d_in[0];
    const float* style   = (const float*)d_in[1];
    const float* w1a     = (const float*)d_in[2];
    const float* alpha1  = (const float*)d_in[3];
    const float* w1b     = (const float*)d_in[4];
    const float* w2a     = (const float*)d_in[5];
    const float* alpha2  = (const float*)d_in[6];
    const float* w2b     = (const float*)d_in[7];
    const float* mod_w   = (const float*)d_in[8];
    const float* mod_b   = (const float*)d_in[9];
    const float* conv_w  = (const float*)d_in[10];
    const float* fused_b = (const float*)d_in[11];
    float* out = (float*)d_out;

    char* ws = (char*)d_ws;
    float*  zbf   = (float*)ws;                  // 256 B zero buffer
    float*  sbuf  = (float*)(ws + 256);          // 512 f
    float*  demod = (float*)(ws + 2304);         // 512 f
    ushort* wfix  = (ushort*)(ws + 4352);        // 4 x 147456 B images
    ushort* wmod  = (ushort*)(ws + 594176);      // 8 x 147456 B
    char*   pl    = ws + 1774080;
    const size_t PAIRB = 134217728ull;           // one H+L plane pair (bytes)
    const size_t PLEL  = 33554432ull;            // elements per plane

    ushort* XPH = (ushort*)pl;             ushort* XPL = XPH + PLEL;
    ushort* PBH = (ushort*)(pl + PAIRB);   ushort* PBL = PBH + PLEL;
    ushort *PAH, *PAL;
    if (ws_size >= 1774080ull + 3 * PAIRB) {
        PAH = (ushort*)(pl + 2 * PAIRB); PAL = PAH + PLEL;
    } else {
        PAH = (ushort*)d_out; PAL = PAH + PLEL;  // d_out hosts PA; rewritten by c5
    }
    const ushort* zb = (const ushort*)zbf;

    // --- prep ---
    hipLaunchKernelGGL(zero_k, dim3(1), dim3(64), 0, stream, zbf);
    hipLaunchKernelGGL(tocl_k, dim3(BB * 1024), dim3(256), 0, stream, x, XPH, XPL);
    hipLaunchKernelGGL(packw_k, dim3(288), dim3(256), 0, stream, w1a, wfix + 0 * 73728);
    hipLaunchKernelGGL(packw_k, dim3(288), dim3(256), 0, stream, w1b, wfix + 1 * 73728);
    hipLaunchKernelGGL(packw_k, dim3(288), dim3(256), 0, stream, w2a, wfix + 2 * 73728);
    hipLaunchKernelGGL(packw_k, dim3(288), dim3(256), 0, stream, w2b, wfix + 3 * 73728);
    hipLaunchKernelGGL(style_s_k, dim3(1), dim3(512), 0, stream, style, mod_w, mod_b, sbuf);
    hipLaunchKernelGGL(demod_k, dim3(1), dim3(512), 0, stream, conv_w, sbuf, demod);
    hipLaunchKernelGGL(packmod_k, dim3(2304), dim3(256), 0, stream, conv_w, sbuf, demod, wmod);

    // --- conv chain ---
    const dim3 cgrid(2048), cblk(256);
    // c1: t1 = prelu(conv(x, w1a))           XP -> PA
    hipLaunchKernelGGL((mconv_k<0, 0>), cgrid, cblk, 0, stream,
        XPH, XPL, (const char*)(wfix + 0 * 73728), alpha1, (const ushort*)nullptr, (const ushort*)nullptr,
        PAH, PAL, (float*)nullptr, zb);
    // c2: h1 = x + conv(t1, w1b)             PA -> PB  (resid XP)
    hipLaunchKernelGGL((mconv_k<1, 0>), cgrid, cblk, 0, stream,
        PAH, PAL, (const char*)(wfix + 1 * 73728), (const float*)nullptr, XPH, XPL,
        PBH, PBL, (float*)nullptr, zb);
    // c3: t2 = prelu(conv(h1, w2a))          PB -> PA
    hipLaunchKernelGGL((mconv_k<0, 0>), cgrid, cblk, 0, stream,
        PBH, PBL, (const char*)(wfix + 2 * 73728), alpha2, (const ushort*)nullptr, (const ushort*)nullptr,
        PAH, PAL, (float*)nullptr, zb);
    // c4: h2 = h1 + conv(t2, w2b)            PA -> PB  (resid PB, in-place same-index)
    hipLaunchKernelGGL((mconv_k<1, 0>), cgrid, cblk, 0, stream,
        PAH, PAL, (const char*)(wfix + 3 * 73728), (const float*)nullptr, PBH, PBL,
        PBH, PBL, (float*)nullptr, zb);
    // c5: out = fused_lrelu(modconv(h2)+b)   PB -> out (NCHW fp32)
    hipLaunchKernelGGL((mconv_k<2, 1>), cgrid, cblk, 0, stream,
        PBH, PBL, (const char*)wmod, fused_b, (const ushort*)nullptr, (const ushort*)nullptr,
        (ushort*)nullptr, (ushort*)nullptr, out, zb);
}